// Round 3
// baseline (105.515 us; speedup 1.0000x reference)
//
#include <hip/hip_runtime.h>

#define NUM_CLASSES 26
#define SUBS 8                        // sub-histograms per counter to cut same-address serialization
#define NCOUNT (3 * NUM_CLASSES)      // 78 global counters
#define LDSN (NCOUNT * SUBS)          // 624 LDS counters
#define DONE_IDX NCOUNT               // gc[78] = arrival counter
#define TPB 256
#define BATCH 6

__global__ void sdl_zero(unsigned int* __restrict__ c) {
    int i = threadIdx.x;
    if (i < NCOUNT + 1) c[i] = 0u;
}

#define HIDX(hist, cls) ((((hist) * NUM_CLASSES) + (cls)) * SUBS + sub)
#define PROC_PAIR(aa, bb)                                                   \
    do {                                                                    \
        atomicAdd(&h[HIDX(0, (aa).x)], 1u);                                 \
        atomicAdd(&h[HIDX(0, (aa).y)], 1u);                                 \
        atomicAdd(&h[HIDX(0, (aa).z)], 1u);                                 \
        atomicAdd(&h[HIDX(0, (aa).w)], 1u);                                 \
        atomicAdd(&h[HIDX(1, (bb).x)], 1u);                                 \
        atomicAdd(&h[HIDX(1, (bb).y)], 1u);                                 \
        atomicAdd(&h[HIDX(1, (bb).z)], 1u);                                 \
        atomicAdd(&h[HIDX(1, (bb).w)], 1u);                                 \
        if ((aa).x == (bb).x) atomicAdd(&h[HIDX(2, (aa).x)], 1u);           \
        if ((aa).y == (bb).y) atomicAdd(&h[HIDX(2, (aa).y)], 1u);           \
        if ((aa).z == (bb).z) atomicAdd(&h[HIDX(2, (aa).z)], 1u);           \
        if ((aa).w == (bb).w) atomicAdd(&h[HIDX(2, (aa).w)], 1u);           \
    } while (0)

__global__ __launch_bounds__(TPB) void sdl_hist(
    const int4* __restrict__ f4, const int4* __restrict__ m4,
    unsigned int* __restrict__ gc, float* __restrict__ out,
    int n4, int sweeps, int tail_start) {
    __shared__ unsigned int h[LDSN];
    for (int i = threadIdx.x; i < LDSN; i += TPB) h[i] = 0u;
    __syncthreads();

    const int tid      = blockIdx.x * TPB + threadIdx.x;
    const int nthreads = gridDim.x * TPB;
    const int sub      = threadIdx.x & (SUBS - 1);
    const int sweep_stride = nthreads * BATCH;

    int4 a[BATCH], b[BATCH];
    int base = tid;

    if (sweeps > 0) {
        #pragma unroll
        for (int k = 0; k < BATCH; ++k) a[k] = f4[base + k * nthreads];
        #pragma unroll
        for (int k = 0; k < BATCH; ++k) b[k] = m4[base + k * nthreads];
    }
    for (int s = 0; s < sweeps; ++s) {
        int4 na[BATCH], nb[BATCH];
        const int nbase = base + sweep_stride;
        if (s + 1 < sweeps) {            // prefetch next sweep: 12 loads in flight
            #pragma unroll
            for (int k = 0; k < BATCH; ++k) na[k] = f4[nbase + k * nthreads];
            #pragma unroll
            for (int k = 0; k < BATCH; ++k) nb[k] = m4[nbase + k * nthreads];
        }
        #pragma unroll
        for (int k = 0; k < BATCH; ++k) {
            int4 aa = a[k], bb = b[k];
            PROC_PAIR(aa, bb);
        }
        if (s + 1 < sweeps) {
            #pragma unroll
            for (int k = 0; k < BATCH; ++k) { a[k] = na[k]; b[k] = nb[k]; }
        }
        base = nbase;
    }
    // generic tail (empty for the benchmarked shape)
    for (int i = tail_start + tid; i < n4; i += nthreads) {
        int4 aa = f4[i], bb = m4[i];
        PROC_PAIR(aa, bb);
    }

    __syncthreads();
    for (int i = threadIdx.x; i < NCOUNT; i += TPB) {
        unsigned int v = 0;
        #pragma unroll
        for (int s2 = 0; s2 < SUBS; ++s2) v += h[i * SUBS + s2];
        if (v) atomicAdd(&gc[i], v);
    }

    // last-block finalize
    __threadfence();
    __shared__ int is_last;
    if (threadIdx.x == 0) {
        unsigned int old = atomicAdd(&gc[DONE_IDX], 1u);
        is_last = (old == (unsigned int)(gridDim.x - 1)) ? 1 : 0;
    }
    __syncthreads();
    if (is_last) {
        __shared__ float vals[NCOUNT];
        if (threadIdx.x < NCOUNT)
            vals[threadIdx.x] = (float)atomicAdd(&gc[threadIdx.x], 0u);  // coherent read
        __syncthreads();
        if (threadIdx.x == 0) {
            const float eps = 1e-5f;
            float ssum = 0.f;
            for (int c = 1; c < NUM_CLASSES; ++c) {
                float F = vals[c];
                float M = vals[NUM_CLASSES + c];
                float I = vals[2 * NUM_CLASSES + c];
                ssum += (2.f * I + eps) / (F + M + eps);
            }
            out[0] = 1.f - ssum / (float)(NUM_CLASSES - 1);
        }
    }
}

extern "C" void kernel_launch(void* const* d_in, const int* in_sizes, int n_in,
                              void* d_out, int out_size, void* d_ws, size_t ws_size,
                              hipStream_t stream) {
    const int* f = (const int*)d_in[0];
    const int* m = (const int*)d_in[1];
    unsigned int* gc = (unsigned int*)d_ws;
    float* out = (float*)d_out;

    int n  = in_sizes[0];         // 14,155,776 (divisible by 4)
    int n4 = n / 4;               // 3,538,944 int4-pairs

    sdl_zero<<<1, 128, 0, stream>>>(gc);

    const int blocks = 768;       // exactly 3 blocks/CU on 256 CUs
    const int nthreads = blocks * TPB;           // 196,608
    const int sweep_stride = nthreads * BATCH;   // 1,179,648
    int sweeps = n4 / sweep_stride;              // 3 for the benchmarked shape
    int tail_start = sweeps * sweep_stride;      // == n4 here (empty tail)

    sdl_hist<<<blocks, TPB, 0, stream>>>((const int4*)f, (const int4*)m,
                                         gc, out, n4, sweeps, tail_start);
}